// Round 1
// baseline (473.787 us; speedup 1.0000x reference)
//
#include <hip/hip_runtime.h>
#include <hip/hip_bf16.h>
#include <stdint.h>

typedef __bf16 bf16;
typedef __bf16 bf16x8 __attribute__((ext_vector_type(8)));
typedef __bf16 bf16x4 __attribute__((ext_vector_type(4)));
typedef float f32x4 __attribute__((ext_vector_type(4)));

#define BM 128
#define BN 128
#define BK 64

// ---------- async global->LDS staging (16B/lane, wave-linear dest) ----------
__device__ __forceinline__ void gload_lds16(const bf16* g, bf16* l) {
    __builtin_amdgcn_global_load_lds(
        (const __attribute__((address_space(1))) void*)g,
        (__attribute__((address_space(3))) void*)l, 16, 0, 0);
}

// Stage a 128x64 bf16 tile (row-major, ld = row stride in elements) into LDS.
// 1024 chunks of 16B; 256 threads x 4 chunks; chunk c = i*256 + t keeps the
// LDS destination wave-linear (base + lane*16).
__device__ __forceinline__ void stage128x64(const bf16* __restrict__ g, int ld,
                                            bf16* l, int t) {
#pragma unroll
    for (int i = 0; i < 4; ++i) {
        int c = (i << 8) + t;
        gload_lds16(g + (size_t)(c >> 3) * ld + ((c & 7) << 3), l + c * 8);
    }
}

// One BK=64 slab of MFMAs: 4 m-frags x 4 n-frags x 2 k-subtiles.
__device__ __forceinline__ void mma_block(const bf16* As, const bf16* Bs,
                                          f32x4 acc[4][4], int lane, int wm, int wn) {
    const int rA = wm * 64 + (lane & 15);
    const int rB = wn * 64 + (lane & 15);
    const int kb = (lane >> 4) * 8;
#pragma unroll
    for (int kk = 0; kk < 2; ++kk) {
        bf16x8 a[4], b[4];
#pragma unroll
        for (int mi = 0; mi < 4; ++mi)
            a[mi] = *(const bf16x8*)&As[(rA + mi * 16) * BK + kk * 32 + kb];
#pragma unroll
        for (int ni = 0; ni < 4; ++ni)
            b[ni] = *(const bf16x8*)&Bs[(rB + ni * 16) * BK + kk * 32 + kb];
#pragma unroll
        for (int mi = 0; mi < 4; ++mi)
#pragma unroll
            for (int ni = 0; ni < 4; ++ni)
                acc[mi][ni] = __builtin_amdgcn_mfma_f32_16x16x32_bf16(
                    a[mi], b[ni], acc[mi][ni], 0, 0, 0);
    }
}

// ---------- prep kernels ----------
__global__ void prep_alpha(const float* __restrict__ a, float* __restrict__ out) {
    int i = blockIdx.x * blockDim.x + threadIdx.x;
    if (i < 1024) out[i] = 0.5f / (1.0f + __expf(-a[i]));
}

__global__ void prep_adj(const float* __restrict__ adj, const float* __restrict__ ahs,
                         bf16* __restrict__ adjb) {
    int i = blockIdx.x * blockDim.x + threadIdx.x;  // 0..262143 (float4 index)
    int row = i >> 8;                               // 256 float4 per 1024-row
    float s = ahs[row];
    float4 v = ((const float4*)adj)[i];
    bf16x4 o = {(bf16)(s * v.x), (bf16)(s * v.y), (bf16)(s * v.z), (bf16)(s * v.w)};
    ((bf16x4*)adjb)[i] = o;
}

__global__ void cast_f32_bf16x4(const float* __restrict__ src, bf16* __restrict__ dst,
                                int n4) {
    int i = blockIdx.x * blockDim.x + threadIdx.x;
    if (i < n4) {
        float4 v = ((const float4*)src)[i];
        bf16x4 o = {(bf16)v.x, (bf16)v.y, (bf16)v.z, (bf16)v.w};
        ((bf16x4*)dst)[i] = o;
    }
}

// weffT[j][k] = w_eff[k][j] = sum_c w[k][c]*clamp(d[c],0,1)*w[j][c]
__global__ void prep_weff(const float* __restrict__ w, const float* __restrict__ dv,
                          bf16* __restrict__ weffT) {
    __shared__ float wk[256];
    __shared__ float dd[256];
    int k = blockIdx.x, j = threadIdx.x;
    dd[j] = fminf(fmaxf(dv[j], 0.0f), 1.0f);
    wk[j] = w[k * 256 + j];
    __syncthreads();
    float s = 0.0f;
#pragma unroll 8
    for (int c = 0; c < 256; ++c) s += wk[c] * dd[c] * w[j * 256 + c];
    weffT[j * 256 + k] = (bf16)s;
}

// ---------- fc_in GEMM: h0 = x @ fcw^T + b ----------
__launch_bounds__(256)
__global__ void gemm_fcin(const bf16* __restrict__ xb, const bf16* __restrict__ fcwb,
                          const float* __restrict__ fcb, float* __restrict__ hf,
                          bf16* __restrict__ hb, bf16* __restrict__ hT) {
    __shared__ __align__(16) bf16 As[BM * BK];
    __shared__ __align__(16) bf16 Bs[BN * BK];
    int t = threadIdx.x, lane = t & 63, wv = t >> 6, wm = wv >> 1, wn = wv & 1;
    int row0 = blockIdx.y * BM;  // 0..32767 (b*1024+n flattened)
    int col0 = blockIdx.x * BN;
    f32x4 acc[4][4] = {};
    const bf16* Ab = xb + (size_t)row0 * 256;
    const bf16* Bb = fcwb + (size_t)col0 * 256;
    for (int kt = 0; kt < 4; ++kt) {
        __syncthreads();
        stage128x64(Ab + kt * BK, 256, As, t);
        stage128x64(Bb + kt * BK, 256, Bs, t);
        __syncthreads();
        mma_block(As, Bs, acc, lane, wm, wn);
    }
    int rbase = row0 + wm * 64 + ((lane >> 4) << 2);
    int cbase = col0 + wn * 64 + (lane & 15);
#pragma unroll
    for (int mi = 0; mi < 4; ++mi) {
        int rg = rbase + mi * 16;
#pragma unroll
        for (int ni = 0; ni < 4; ++ni) {
            int col = cbase + ni * 16;
            float bias = fcb[col];
            bf16x4 tv;
#pragma unroll
            for (int r = 0; r < 4; ++r) {
                float v = acc[mi][ni][r] + bias;
                size_t idx = (size_t)(rg + r) * 256 + col;
                hf[idx] = v;
                bf16 vb = (bf16)v;
                hb[idx] = vb;
                tv[r] = vb;
            }
            int b = rg >> 10, n = rg & 1023;
            *(bf16x4*)&hT[(((size_t)(b * 256 + col)) << 10) + n] = tv;
        }
    }
}

// ---------- fused Euler step ----------
// acc = (0.5*sig(alpha)*adj) @ h  +  h @ w_eff        (both bf16 MFMA, fp32 acc)
// h   = h + dt*(acc - (0.5*sig(alpha)+1)*h + x0)
__launch_bounds__(256)
__global__ void gemm_step(const bf16* __restrict__ adjb, const bf16* __restrict__ hbp,
                          const bf16* __restrict__ hTp, const bf16* __restrict__ weffT,
                          const float* __restrict__ ahs, const float* __restrict__ x0,
                          float* __restrict__ hf, bf16* __restrict__ hbn,
                          bf16* __restrict__ hTn) {
    __shared__ __align__(16) bf16 As[BM * BK];
    __shared__ __align__(16) bf16 Bs[BN * BK];
    int t = threadIdx.x, lane = t & 63, wv = t >> 6, wm = wv >> 1, wn = wv & 1;
    int n0 = blockIdx.y * BM;
    int d0 = blockIdx.x * BN;
    int b = blockIdx.z;
    f32x4 acc[4][4] = {};

    // phase 1: adj_scaled[n0:,:1024] @ h[b] via hT (K = 1024)
    const bf16* Ab1 = adjb + (size_t)n0 * 1024;
    const bf16* Bb1 = hTp + ((size_t)(b * 256 + d0)) * 1024;
    for (int kt = 0; kt < 16; ++kt) {
        __syncthreads();
        stage128x64(Ab1 + kt * BK, 1024, As, t);
        stage128x64(Bb1 + kt * BK, 1024, Bs, t);
        __syncthreads();
        mma_block(As, Bs, acc, lane, wm, wn);
    }
    // phase 2: h[b][n0:,:256] @ w_eff (K = 256)
    const bf16* Ab2 = hbp + ((size_t)(b * 1024 + n0)) * 256;
    const bf16* Bb2 = weffT + (size_t)d0 * 256;
    for (int kt = 0; kt < 4; ++kt) {
        __syncthreads();
        stage128x64(Ab2 + kt * BK, 256, As, t);
        stage128x64(Bb2 + kt * BK, 256, Bs, t);
        __syncthreads();
        mma_block(As, Bs, acc, lane, wm, wn);
    }

    const float dt = 0.125f;
    int rb = wm * 64 + ((lane >> 4) << 2);
    int cb = d0 + wn * 64 + (lane & 15);
#pragma unroll
    for (int mi = 0; mi < 4; ++mi) {
        int nr = n0 + rb + mi * 16;  // node row base (4 consecutive rows)
#pragma unroll
        for (int ni = 0; ni < 4; ++ni) {
            int col = cb + ni * 16;
            bf16x4 tv;
#pragma unroll
            for (int r = 0; r < 4; ++r) {
                int node = nr + r;
                size_t idx = (((size_t)b << 10) + node) * 256 + col;
                float hold = hf[idx];
                float f = acc[mi][ni][r] - (ahs[node] + 1.0f) * hold + x0[idx];
                float hv = hold + dt * f;
                hf[idx] = hv;
                bf16 vb = (bf16)hv;
                hbn[idx] = vb;
                tv[r] = vb;
            }
            *(bf16x4*)&hTn[(((size_t)(b * 256 + col)) << 10) + nr] = tv;
        }
    }
}

extern "C" void kernel_launch(void* const* d_in, const int* in_sizes, int n_in,
                              void* d_out, int out_size, void* d_ws, size_t ws_size,
                              hipStream_t stream) {
    const float* x     = (const float*)d_in[0];  // [32,1024,256]
    const float* adj   = (const float*)d_in[1];  // [1024,1024]
    const float* alpha = (const float*)d_in[2];  // [1024]
    const float* w     = (const float*)d_in[3];  // [256,256]
    const float* dvec  = (const float*)d_in[4];  // [256]
    const float* fcw   = (const float*)d_in[5];  // [256,256]
    const float* fcb   = (const float*)d_in[6];  // [256]
    float* out = (float*)d_out;                  // h master (fp32), updated in place

    const size_t HB = (size_t)32 * 1024 * 256 * 2;  // 16 MiB
    char* p = (char*)d_ws;
    bf16* hb0   = (bf16*)p; p += HB;
    bf16* hb1   = (bf16*)p; p += HB;
    bf16* hT0   = (bf16*)p; p += HB;
    bf16* hT1   = (bf16*)p; p += HB;
    bf16* xb    = (bf16*)p; p += HB;
    bf16* adjb  = (bf16*)p; p += (size_t)1024 * 1024 * 2;
    bf16* fcwb  = (bf16*)p; p += 256 * 256 * 2;
    bf16* weffT = (bf16*)p; p += 256 * 256 * 2;
    float* ahs  = (float*)p; p += 1024 * 4;

    prep_alpha<<<4, 256, 0, stream>>>(alpha, ahs);
    prep_adj<<<1024, 256, 0, stream>>>(adj, ahs, adjb);
    prep_weff<<<256, 256, 0, stream>>>(w, dvec, weffT);
    cast_f32_bf16x4<<<8192, 256, 0, stream>>>(x, xb, 2097152);
    cast_f32_bf16x4<<<64, 256, 0, stream>>>(fcw, fcwb, 16384);

    gemm_fcin<<<dim3(2, 256), 256, 0, stream>>>(xb, fcwb, fcb, out, hb0, hT0);

    bf16* hb[2] = {hb0, hb1};
    bf16* hT[2] = {hT0, hT1};
    int cur = 0;
    for (int s = 0; s < 8; ++s) {
        gemm_step<<<dim3(2, 8, 32), 256, 0, stream>>>(
            adjb, hb[cur], hT[cur], weffT, ahs, x, out, hb[cur ^ 1], hT[cur ^ 1]);
        cur ^= 1;
    }
}

// Round 2
// 451.861 us; speedup vs baseline: 1.0485x; 1.0485x over previous
//
#include <hip/hip_runtime.h>
#include <hip/hip_bf16.h>
#include <stdint.h>

typedef __bf16 bf16;
typedef __bf16 bf16x8 __attribute__((ext_vector_type(8)));
typedef __bf16 bf16x4 __attribute__((ext_vector_type(4)));
typedef float f32x4 __attribute__((ext_vector_type(4)));

#define BM 128
#define BN 64
#define BK 64

// ---------- async global->LDS staging (16B/lane, wave-linear dest) ----------
__device__ __forceinline__ void gload_lds16(const bf16* g, bf16* l) {
    __builtin_amdgcn_global_load_lds(
        (const __attribute__((address_space(1))) void*)g,
        (__attribute__((address_space(3))) void*)l, 16, 0, 0);
}

// Stage an R x 64 bf16 tile (row-major, ld elements) into LDS; CH = R*8 16B chunks.
template <int CH>
__device__ __forceinline__ void stageT(const bf16* __restrict__ g, int ld,
                                       bf16* l, int t) {
#pragma unroll
    for (int i = 0; i < CH / 256; ++i) {
        int c = (i << 8) + t;
        gload_lds16(g + (size_t)(c >> 3) * ld + ((c & 7) << 3), l + c * 8);
    }
}

// One BK=64 slab: 128x64 output, 4 waves as 2x2, wave tile 64x32.
__device__ __forceinline__ void mma_128x64(const bf16* As, const bf16* Bs,
                                           f32x4 acc[4][2], int lane, int wm, int wn) {
    const int rA = wm * 64 + (lane & 15);
    const int rB = wn * 32 + (lane & 15);
    const int kb = (lane >> 4) * 8;
#pragma unroll
    for (int kk = 0; kk < 2; ++kk) {
        bf16x8 a[4], b[2];
#pragma unroll
        for (int mi = 0; mi < 4; ++mi)
            a[mi] = *(const bf16x8*)&As[(rA + mi * 16) * BK + kk * 32 + kb];
#pragma unroll
        for (int ni = 0; ni < 2; ++ni)
            b[ni] = *(const bf16x8*)&Bs[(rB + ni * 16) * BK + kk * 32 + kb];
#pragma unroll
        for (int mi = 0; mi < 4; ++mi)
#pragma unroll
            for (int ni = 0; ni < 2; ++ni)
                acc[mi][ni] = __builtin_amdgcn_mfma_f32_16x16x32_bf16(
                    a[mi], b[ni], acc[mi][ni], 0, 0, 0);
    }
}

// ---------- prep kernels ----------
__global__ void prep_alpha(const float* __restrict__ a, float* __restrict__ out) {
    int i = blockIdx.x * blockDim.x + threadIdx.x;
    if (i < 1024) out[i] = 0.5f / (1.0f + __expf(-a[i]));
}

__global__ void prep_adj(const float* __restrict__ adj, const float* __restrict__ ahs,
                         bf16* __restrict__ adjb) {
    int i = blockIdx.x * blockDim.x + threadIdx.x;  // float4 index
    int row = i >> 8;
    float s = ahs[row];
    float4 v = ((const float4*)adj)[i];
    bf16x4 o = {(bf16)(s * v.x), (bf16)(s * v.y), (bf16)(s * v.z), (bf16)(s * v.w)};
    ((bf16x4*)adjb)[i] = o;
}

__global__ void cast_f32_bf16x4(const float* __restrict__ src, bf16* __restrict__ dst,
                                int n4) {
    int i = blockIdx.x * blockDim.x + threadIdx.x;
    if (i < n4) {
        float4 v = ((const float4*)src)[i];
        bf16x4 o = {(bf16)v.x, (bf16)v.y, (bf16)v.z, (bf16)v.w};
        ((bf16x4*)dst)[i] = o;
    }
}

// weffT[j][k] = w_eff[k][j] (w_eff symmetric anyway)
__global__ void prep_weff(const float* __restrict__ w, const float* __restrict__ dv,
                          bf16* __restrict__ weffT) {
    __shared__ float wk[256];
    __shared__ float dd[256];
    int k = blockIdx.x, j = threadIdx.x;
    dd[j] = fminf(fmaxf(dv[j], 0.0f), 1.0f);
    wk[j] = w[k * 256 + j];
    __syncthreads();
    float s = 0.0f;
#pragma unroll 8
    for (int c = 0; c < 256; ++c) s += wk[c] * dd[c] * w[j * 256 + c];
    weffT[j * 256 + k] = (bf16)s;
}

// ---------- fc_in GEMM: h0 = x @ fcw^T + b ----------
__launch_bounds__(256)
__global__ void gemm_fcin(const bf16* __restrict__ xb, const bf16* __restrict__ fcwb,
                          const float* __restrict__ fcb, float* __restrict__ hf,
                          bf16* __restrict__ hb, bf16* __restrict__ hT) {
    __shared__ __align__(16) bf16 As[BM * BK];
    __shared__ __align__(16) bf16 Bs[BN * BK];
    int t = threadIdx.x, lane = t & 63, wv = t >> 6, wm = wv >> 1, wn = wv & 1;
    int row0 = blockIdx.y * BM;  // flattened b*1024+n
    int col0 = blockIdx.x * BN;
    f32x4 acc[4][2] = {};
    const bf16* Ab = xb + (size_t)row0 * 256;
    const bf16* Bb = fcwb + (size_t)col0 * 256;
    for (int kt = 0; kt < 4; ++kt) {
        __syncthreads();
        stageT<1024>(Ab + kt * BK, 256, As, t);
        stageT<512>(Bb + kt * BK, 256, Bs, t);
        __syncthreads();
        mma_128x64(As, Bs, acc, lane, wm, wn);
    }
    int rbase = row0 + wm * 64 + ((lane >> 4) << 2);
    int cbase = col0 + wn * 32 + (lane & 15);
#pragma unroll
    for (int mi = 0; mi < 4; ++mi) {
        int rg = rbase + mi * 16;
#pragma unroll
        for (int ni = 0; ni < 2; ++ni) {
            int col = cbase + ni * 16;
            float bias = fcb[col];
            bf16x4 tv;
#pragma unroll
            for (int r = 0; r < 4; ++r) {
                float v = acc[mi][ni][r] + bias;
                size_t idx = (size_t)(rg + r) * 256 + col;
                hf[idx] = v;
                bf16 vb = (bf16)v;
                hb[idx] = vb;
                tv[r] = vb;
            }
            int b = rg >> 10, n = rg & 1023;
            *(bf16x4*)&hT[(((size_t)(b * 256 + col)) << 10) + n] = tv;
        }
    }
}

// ---------- fused Euler step ----------
// acc = (0.5*sig(alpha)*adj) @ h  +  h @ w_eff   (bf16 MFMA, fp32 acc)
// h   = h + dt*(acc - (0.5*sig(alpha)+1)*h + x0)
__launch_bounds__(256)
__global__ void gemm_step(const bf16* __restrict__ adjb, const bf16* __restrict__ hbp,
                          const bf16* __restrict__ hTp, const bf16* __restrict__ weffT,
                          const float* __restrict__ ahs, const bf16* __restrict__ x0b,
                          float* __restrict__ hf, bf16* __restrict__ hbn,
                          bf16* __restrict__ hTn) {
    __shared__ __align__(16) bf16 As[BM * BK];
    __shared__ __align__(16) bf16 Bs[BN * BK];
    int t = threadIdx.x, lane = t & 63, wv = t >> 6, wm = wv >> 1, wn = wv & 1;
    // 1D grid, XCD-aware decode: all tiles of batch b land on XCD b%8.
    int g = blockIdx.x;
    int xcd = g & 7, rest = g >> 3;
    int xy = rest & 31, bhi = rest >> 5;
    int b = bhi * 8 + xcd;
    int d0 = (xy & 3) * BN;
    int n0 = (xy >> 2) * BM;
    f32x4 acc[4][2] = {};

    // phase 1: adj_scaled[n0:,:1024] @ h[b] via hT (K = 1024)
    const bf16* Ab1 = adjb + (size_t)n0 * 1024;
    const bf16* Bb1 = hTp + ((size_t)(b * 256 + d0)) * 1024;
    for (int kt = 0; kt < 16; ++kt) {
        __syncthreads();
        stageT<1024>(Ab1 + kt * BK, 1024, As, t);
        stageT<512>(Bb1 + kt * BK, 1024, Bs, t);
        __syncthreads();
        mma_128x64(As, Bs, acc, lane, wm, wn);
    }
    // phase 2: h[b][n0:,:256] @ w_eff (K = 256)
    const bf16* Ab2 = hbp + ((size_t)(b * 1024 + n0)) * 256;
    const bf16* Bb2 = weffT + (size_t)d0 * 256;
    for (int kt = 0; kt < 4; ++kt) {
        __syncthreads();
        stageT<1024>(Ab2 + kt * BK, 256, As, t);
        stageT<512>(Bb2 + kt * BK, 256, Bs, t);
        __syncthreads();
        mma_128x64(As, Bs, acc, lane, wm, wn);
    }

    const float dt = 0.125f;
    int rb = wm * 64 + ((lane >> 4) << 2);
    int cb = d0 + wn * 32 + (lane & 15);
#pragma unroll
    for (int mi = 0; mi < 4; ++mi) {
        int nr = n0 + rb + mi * 16;
#pragma unroll
        for (int ni = 0; ni < 2; ++ni) {
            int col = cb + ni * 16;
            bf16x4 tv;
#pragma unroll
            for (int r = 0; r < 4; ++r) {
                int node = nr + r;
                size_t idx = (((size_t)b << 10) + node) * 256 + col;
                float hold = hf[idx];
                float x0v = (float)x0b[idx];
                float f = acc[mi][ni][r] - (ahs[node] + 1.0f) * hold + x0v;
                float hv = hold + dt * f;
                hf[idx] = hv;
                bf16 vb = (bf16)hv;
                hbn[idx] = vb;
                tv[r] = vb;
            }
            *(bf16x4*)&hTn[(((size_t)(b * 256 + col)) << 10) + nr] = tv;
        }
    }
}

extern "C" void kernel_launch(void* const* d_in, const int* in_sizes, int n_in,
                              void* d_out, int out_size, void* d_ws, size_t ws_size,
                              hipStream_t stream) {
    const float* x     = (const float*)d_in[0];  // [32,1024,256]
    const float* adj   = (const float*)d_in[1];  // [1024,1024]
    const float* alpha = (const float*)d_in[2];  // [1024]
    const float* w     = (const float*)d_in[3];  // [256,256]
    const float* dvec  = (const float*)d_in[4];  // [256]
    const float* fcw   = (const float*)d_in[5];  // [256,256]
    const float* fcb   = (const float*)d_in[6];  // [256]
    float* out = (float*)d_out;                  // h master (fp32), updated in place

    const size_t HB = (size_t)32 * 1024 * 256 * 2;  // 16 MiB
    char* p = (char*)d_ws;
    bf16* hb0   = (bf16*)p; p += HB;
    bf16* hb1   = (bf16*)p; p += HB;
    bf16* hT0   = (bf16*)p; p += HB;
    bf16* hT1   = (bf16*)p; p += HB;
    bf16* xb    = (bf16*)p; p += HB;
    bf16* adjb  = (bf16*)p; p += (size_t)1024 * 1024 * 2;
    bf16* fcwb  = (bf16*)p; p += 256 * 256 * 2;
    bf16* weffT = (bf16*)p; p += 256 * 256 * 2;
    float* ahs  = (float*)p; p += 1024 * 4;

    prep_alpha<<<4, 256, 0, stream>>>(alpha, ahs);
    prep_adj<<<1024, 256, 0, stream>>>(adj, ahs, adjb);
    prep_weff<<<256, 256, 0, stream>>>(w, dvec, weffT);
    cast_f32_bf16x4<<<8192, 256, 0, stream>>>(x, xb, 2097152);
    cast_f32_bf16x4<<<64, 256, 0, stream>>>(fcw, fcwb, 16384);

    gemm_fcin<<<dim3(4, 256), 256, 0, stream>>>(xb, fcwb, fcb, out, hb0, hT0);

    bf16* hb[2] = {hb0, hb1};
    bf16* hT[2] = {hT0, hT1};
    int cur = 0;
    for (int s = 0; s < 8; ++s) {
        gemm_step<<<1024, 256, 0, stream>>>(
            adjb, hb[cur], hT[cur], weffT, ahs, xb, out, hb[cur ^ 1], hT[cur ^ 1]);
        cur ^= 1;
    }
}